// Round 10
// baseline (101.964 us; speedup 1.0000x reference)
//
#include <hip/hip_runtime.h>
#include <hip/hip_bf16.h>

// 3D conv K=2 VALID + (y+1)^2, mfma_f32_32x32x16_bf16, vectorized streams.
// x: (8,16,64,64,64) f32; w: (32,128) f32, k = c*8 + kd*4 + kh*2 + kw.
// out: (8,32,63,63,63) f32.
//
// R9 structure with h-tile 8 -> 4 for occupancy (TLP experiment):
//  - tile [2kd][2kh8][5h][64w][8c] bf16 = 20,480 B; strip 4 KB; total
//    24,576 B -> 5 blocks/CU (20 waves), __launch_bounds__(256,5).
//  - wave wv owns h-row wv (x 2 w-halves): acc = 2 x f32x16 = 32 VGPR.
//  - epilogue runs = 4h x 63w = 252 dw: head + ONE dwordx4 round + tail.
//  - everything else per R9: dwordx4 global loads, wave-private 2-stage
//    LDS transpose, conflict-free tile layout (w-stride 16 B), NT stores,
//    shift-aligned drain, linear grid (d-neighbors 16 bids apart -> same
//    XCD -> slab L2 reuse).

typedef __attribute__((ext_vector_type(8)))  short short8;
typedef __attribute__((ext_vector_type(4)))  float f32x4;
typedef __attribute__((ext_vector_type(16))) float f32x16;
typedef __attribute__((ext_vector_type(4)))  unsigned short u16x4;

#define XCS 262144        // 64^3 x channel stride (f32)
#define OS  250047        // 63^3 out channel stride (f32)
#define KD_E   5120       // u16 per kd slab: [2 kh8][5 h][64 w][8 c]
#define KH8_E  2560       // 5*64*8
#define STRIP_OFF 20480   // byte offset of strip
#define IMG_DW 260        // dwords per epilogue run slot (252 + shift pad)

__device__ __forceinline__ unsigned short f2bf(float f) {
    unsigned int u = __builtin_bit_cast(unsigned int, f);
    return (unsigned short)((u + 0x7fffu + ((u >> 16) & 1u)) >> 16);
}

__global__ __launch_bounds__(256, 5) void conv3d_k2_h4(
    const float* __restrict__ x,
    const float* __restrict__ wgt,
    float* __restrict__ out)
{
    __shared__ __align__(16) unsigned char lds_raw[24576];
    unsigned short* tile  = (unsigned short*)lds_raw;               // [2][2][5][64][8] u16
    unsigned short* strip = (unsigned short*)(lds_raw + STRIP_OFF); // [2][16c][64w] u16
    float* img = (float*)lds_raw;                                    // [16][260] f32

    const int t   = threadIdx.x;
    const int l   = t & 63;
    const int wv  = t >> 6;        // wave 0..3 -> h row
    const int col = l & 31;        // MFMA col (w) / A row (o)
    const int kh8 = l >> 5;        // k-half -> c8 group

    const int h0 = blockIdx.x * 4; // 4 output h rows (3 valid in tail tile)
    const int d  = blockIdx.y;     // 0..62
    const int b  = blockIdx.z;
    const int hvalid = (h0 == 60) ? 3 : 4;

    // ---- A fragments: 64 contiguous floats per lane, compile-time shuffle ----
    short8 aF[8];
    {
        f32x4 wreg[16];
        const float* wp = wgt + col * 128 + kh8 * 64;
#pragma unroll
        for (int q = 0; q < 16; ++q) wreg[q] = *(const f32x4*)(wp + q * 4);
#pragma unroll
        for (int tap = 0; tap < 8; ++tap) {
            short8 a;
#pragma unroll
            for (int j = 0; j < 8; ++j) {
                const int k = j * 8 + tap;
                a[j] = (short)f2bf(wreg[k >> 2][k & 3]);
            }
            aF[tap] = a;
        }
    }

    // ---- staging: dwordx4 loads + wave-private 2-stage LDS transpose ----
    const int cA   = t >> 4;       // c plane 0..15
    const int wq   = t & 15;       // 16-B w quad
    const int wB   = l;            // stage-B w
    const int kh8s = wv >> 1;
    const int half = wv & 1;

#pragma unroll
    for (int p = 0; p < 2; ++p) {
        const float* xs = x + (size_t)b * 16 * XCS + (size_t)(d + p) * 4096;
        f32x4 v[5];
#pragma unroll
        for (int h = 0; h < 5; ++h) {
            int hp = h0 + h; if (hp > 63) hp = 63;
            v[h] = *(const f32x4*)(xs + (size_t)cA * XCS + hp * 64 + wq * 4);
        }
#pragma unroll
        for (int h = 0; h < 5; ++h) {
            unsigned short* sb = strip + (h & 1) * 1024;
            u16x4 pk;
#pragma unroll
            for (int i = 0; i < 4; ++i) pk[i] = f2bf(v[h][i]);
            *(u16x4*)&sb[cA * 64 + wq * 4] = pk;
            u16x4 q;
#pragma unroll
            for (int i = 0; i < 4; ++i)
                q[i] = sb[(wv * 4 + i) * 64 + wB];
            *(u16x4*)&tile[p * KD_E + kh8s * KH8_E + h * 512 + wB * 8 + half * 4] = q;
        }
    }
    __syncthreads();

    // ---- compute: wave wv = h row; 2 w-halves; acc 2 x f32x16 ----
    f32x16 acc[2];
#pragma unroll
    for (int wh = 0; wh < 2; ++wh) {
        const int wb = wh * 32;
        f32x16 a = {};
#pragma unroll
        for (int kd = 0; kd < 2; ++kd)
#pragma unroll
        for (int kh = 0; kh < 2; ++kh)
#pragma unroll
        for (int kw = 0; kw < 2; ++kw) {
            const int tap = kd * 4 + kh * 2 + kw;
            short8 bfrag = *(const short8*)&tile[kd * KD_E + kh8 * KH8_E
                + (wv + kh) * 512 + (wb + col + kw) * 8];
            a = __builtin_amdgcn_mfma_f32_32x32x16_bf16(aF[tap], bfrag, a, 0, 0, 0);
        }
        acc[wh] = a;
    }
    __syncthreads();   // done reading tile; LDS becomes the store image

    // ---- epilogue: 2 passes x 16 o-runs, shift-aligned NT dwordx4 drain ----
    const int runlen = hvalid * 63;
#pragma unroll
    for (int p = 0; p < 2; ++p) {
        // scatter (y+1)^2 into img, shifted by each run's base&3
        if (wv < hvalid) {
#pragma unroll
            for (int wh = 0; wh < 2; ++wh) {
                const int wc = wh * 32 + col;
                if (wc < 63) {
#pragma unroll
                    for (int r = 0; r < 8; ++r) {
                        const int rr = p * 8 + r;
                        const int og = (rr & 3) + 8 * (rr >> 2) + 4 * kh8;
                        const int ol = og - p * 16;
                        const unsigned sh =
                            (3u * (unsigned)(32 * b + og) + (unsigned)d + 3u * (unsigned)h0) & 3u;
                        float y = acc[wh][rr] + 1.0f;
                        img[ol * IMG_DW + (int)sh + wv * 63 + wc] = y * y;
                    }
                }
            }
        }
        __syncthreads();
        // drain: wave wv owns 4 runs; head(<=3) + 1x NT dwordx4 + tail(<=3)
#pragma unroll
        for (int orun = 0; orun < 4; ++orun) {
            const int ol = wv * 4 + orun;
            const int og = p * 16 + ol;
            const size_t base_dw = ((size_t)b * 32 + og) * (size_t)OS
                                 + (size_t)d * 3969 + (size_t)h0 * 63;
            float* gp = out + base_dw;
            const int sh = (int)(base_dw & 3);
            const int g0 = (4 - sh) & 3;
            const float* ip = img + ol * IMG_DW + sh;
            if (l < g0) __builtin_nontemporal_store(ip[l], gp + l);
            const int nv = (runlen - g0) >> 2;
            if (l < nv) {
                f32x4 qv = *(const f32x4*)(ip + g0 + 4 * l);
                __builtin_nontemporal_store(qv, (f32x4*)(gp + g0 + 4 * l));
            }
            const int kt = g0 + 4 * nv + l;
            if (kt < runlen) __builtin_nontemporal_store(ip[kt], gp + kt);
        }
        if (p == 0) __syncthreads();   // img reused by pass-1 scatter
    }
}

extern "C" void kernel_launch(void* const* d_in, const int* in_sizes, int n_in,
                              void* d_out, int out_size, void* d_ws, size_t ws_size,
                              hipStream_t stream) {
    const float* x   = (const float*)d_in[0];
    const float* wgt = (const float*)d_in[1];
    float* out = (float*)d_out;

    dim3 grid(16, 63, 8);   // h-tiles, d, b (linear = L2-friendly map)
    dim3 block(256);
    conv3d_k2_h4<<<grid, block, 0, stream>>>(x, wgt, out);
}

// Round 11
// 80.865 us; speedup vs baseline: 1.2609x; 1.2609x over previous
//
#include <hip/hip_runtime.h>
#include <hip/hip_bf16.h>

// 3D conv K=2 VALID + (y+1)^2, mfma_f32_32x32x16_bf16, vectorized streams.
// x: (8,16,64,64,64) f32; w: (32,128) f32, k = c*8 + kd*4 + kh*2 + kw.
// out: (8,32,63,63,63) f32.
//
// R9 exactly (best: 83.4 us) + ONE change: the two slabs' global loads are
// issued as a single 18x dwordx4 burst into registers BEFORE any transpose
// work (T14 issue-early/consume-late). R9 serialized slab-1's loads behind
// slab-0's dependent LDS-transpose chain (VGPR=48 proves no compiler hoist),
// exposing ~600 cy of HBM/L2 latency once per block. Now all loads fly
// together and the transpose runs at LDS speed.
//   - tile [2kd][2kh8][9h][64w][8c] bf16 (w-stride 16 B, conflict-free)
//   - strip [2][16c][64w] per-h double buffer, wave-private transpose
//   - LDS 40960 B = exactly 4 blocks/CU; VGPR ~115 < 128 (4 waves/SIMD ok)
//   - NT shift-aligned dwordx4 stores via LDS img, 2 passes
//   - grid (8,63,8) linear: d-neighbors 8 bids apart -> same XCD L2 reuse

typedef __attribute__((ext_vector_type(8)))  short short8;
typedef __attribute__((ext_vector_type(4)))  float f32x4;
typedef __attribute__((ext_vector_type(16))) float f32x16;
typedef __attribute__((ext_vector_type(4)))  unsigned short u16x4;

#define XCS 262144        // 64^3 x channel stride (f32)
#define OS  250047        // 63^3 out channel stride (f32)
#define SLAB_E 9216       // u16 per kd slab: [2 kh8][9 h][64 w][8 c]
#define KH8_E  4608       // 9*64*8
#define IMG_DW 520        // dwords per epilogue run slot (504 + shift pad)

__device__ __forceinline__ unsigned short f2bf(float f) {
    unsigned int u = __builtin_bit_cast(unsigned int, f);
    return (unsigned short)((u + 0x7fffu + ((u >> 16) & 1u)) >> 16);
}

__global__ __launch_bounds__(256, 4) void conv3d_k2_burst(
    const float* __restrict__ x,
    const float* __restrict__ wgt,
    float* __restrict__ out)
{
    __shared__ __align__(16) unsigned char lds_raw[40960];
    unsigned short* tile  = (unsigned short*)lds_raw;            // [2][2][9][64][8] u16
    unsigned short* strip = (unsigned short*)(lds_raw + 36864);  // [2][16c][64w] u16
    float* img = (float*)lds_raw;                                 // [16][520] f32

    const int t   = threadIdx.x;
    const int l   = t & 63;
    const int wv  = t >> 6;        // wave 0..3
    const int col = l & 31;        // MFMA col (w) / A row (o)
    const int kh8 = l >> 5;        // k-half -> c8 group

    const int h0 = blockIdx.x * 8; // 8 output h rows
    const int d  = blockIdx.y;     // 0..62
    const int b  = blockIdx.z;

    // ---- A fragments: 64 contiguous floats per lane, compile-time shuffle ----
    short8 aF[8];
    {
        f32x4 wreg[16];
        const float* wp = wgt + col * 128 + kh8 * 64;
#pragma unroll
        for (int q = 0; q < 16; ++q) wreg[q] = *(const f32x4*)(wp + q * 4);
#pragma unroll
        for (int tap = 0; tap < 8; ++tap) {
            short8 a;
#pragma unroll
            for (int j = 0; j < 8; ++j) {
                const int k = j * 8 + tap;
                a[j] = (short)f2bf(wreg[k >> 2][k & 3]);
            }
            aF[tap] = a;
        }
    }

    // ---- staging: ONE 18x dwordx4 burst (both slabs), then LDS transpose ----
    const int cA   = t >> 4;       // c plane 0..15
    const int wq   = t & 15;       // 16-B w quad
    const int wB   = l;            // stage-B w
    const int kh8s = wv >> 1;
    const int half = wv & 1;

    f32x4 v[2][9];
#pragma unroll
    for (int p = 0; p < 2; ++p) {
        const float* xs = x + (size_t)b * 16 * XCS + (size_t)(d + p) * 4096
                            + (size_t)cA * XCS + wq * 4;
#pragma unroll
        for (int h = 0; h < 9; ++h) {
            int hp = h0 + h; if (hp > 63) hp = 63;
            v[p][h] = *(const f32x4*)(xs + hp * 64);
        }
    }

#pragma unroll
    for (int p = 0; p < 2; ++p) {
#pragma unroll
        for (int h = 0; h < 9; ++h) {
            unsigned short* sb = strip + (h & 1) * 1024;
            u16x4 pk;
#pragma unroll
            for (int i = 0; i < 4; ++i) pk[i] = f2bf(v[p][h][i]);
            *(u16x4*)&sb[cA * 64 + wq * 4] = pk;
            u16x4 q;
#pragma unroll
            for (int i = 0; i < 4; ++i)
                q[i] = sb[(wv * 4 + i) * 64 + wB];
            *(u16x4*)&tile[p * SLAB_E + kh8s * KH8_E + h * 512 + wB * 8 + half * 4] = q;
        }
    }
    __syncthreads();

    // ---- compute: 4 acc tiles (2 h-rows x 2 w-halves) kept in regs ----
    f32x16 acc[2][2];
#pragma unroll
    for (int th = 0; th < 2; ++th) {
        const int hl = wv * 2 + th;
#pragma unroll
        for (int wh = 0; wh < 2; ++wh) {
            const int wb = wh * 32;
            f32x16 a = {};
#pragma unroll
            for (int kd = 0; kd < 2; ++kd)
#pragma unroll
            for (int kh = 0; kh < 2; ++kh)
#pragma unroll
            for (int kw = 0; kw < 2; ++kw) {
                const int tap = kd * 4 + kh * 2 + kw;
                short8 bfrag = *(const short8*)&tile[kd * SLAB_E + kh8 * KH8_E
                    + (hl + kh) * 512 + (wb + col + kw) * 8];
                a = __builtin_amdgcn_mfma_f32_32x32x16_bf16(aF[tap], bfrag, a, 0, 0, 0);
            }
            acc[th][wh] = a;
        }
    }
    __syncthreads();   // done reading tile; LDS becomes the store image

    // ---- epilogue: 2 passes x 16 o-runs, shift-aligned NT dwordx4 drain ----
    const int hvalid = (h0 == 56) ? 7 : 8;
    const int runlen = hvalid * 63;
#pragma unroll
    for (int p = 0; p < 2; ++p) {
        // scatter (y+1)^2 into img, shifted by each run's base&3
#pragma unroll
        for (int th = 0; th < 2; ++th) {
            const int hl = wv * 2 + th;
            if (hl < hvalid) {
#pragma unroll
                for (int wh = 0; wh < 2; ++wh) {
                    const int wc = wh * 32 + col;
                    if (wc < 63) {
#pragma unroll
                        for (int r = 0; r < 8; ++r) {
                            const int rr = p * 8 + r;
                            const int og = (rr & 3) + 8 * (rr >> 2) + 4 * kh8;
                            const int ol = og - p * 16;
                            const unsigned sh =
                                (3u * (unsigned)(32 * b + og) + (unsigned)d + 3u * (unsigned)h0) & 3u;
                            float y = acc[th][wh][rr] + 1.0f;
                            img[ol * IMG_DW + (int)sh + hl * 63 + wc] = y * y;
                        }
                    }
                }
            }
        }
        __syncthreads();
        // drain: wave wv owns 4 runs; head(<=3) + 2x NT dwordx4 + tail(<=3)
#pragma unroll
        for (int orun = 0; orun < 4; ++orun) {
            const int ol = wv * 4 + orun;
            const int og = p * 16 + ol;
            const size_t base_dw = ((size_t)b * 32 + og) * (size_t)OS
                                 + (size_t)d * 3969 + (size_t)h0 * 63;
            float* gp = out + base_dw;
            const int sh = (int)(base_dw & 3);
            const int g0 = (4 - sh) & 3;
            const float* ip = img + ol * IMG_DW + sh;
            if (l < g0) __builtin_nontemporal_store(ip[l], gp + l);
            const int nv = (runlen - g0) >> 2;
#pragma unroll
            for (int rnd = 0; rnd < 2; ++rnd) {
                const int k = rnd * 64 + l;
                if (k < nv) {
                    f32x4 qv = *(const f32x4*)(ip + g0 + 4 * k);
                    __builtin_nontemporal_store(qv, (f32x4*)(gp + g0 + 4 * k));
                }
            }
            const int kt = g0 + 4 * nv + l;
            if (kt < runlen) __builtin_nontemporal_store(ip[kt], gp + kt);
        }
        if (p == 0) __syncthreads();   // img reused by pass-1 scatter
    }
}

extern "C" void kernel_launch(void* const* d_in, const int* in_sizes, int n_in,
                              void* d_out, int out_size, void* d_ws, size_t ws_size,
                              hipStream_t stream) {
    const float* x   = (const float*)d_in[0];
    const float* wgt = (const float*)d_in[1];
    float* out = (float*)d_out;

    dim3 grid(8, 63, 8);    // h-tiles, d, b (linear = L2-friendly map)
    dim3 block(256);
    conv3d_k2_burst<<<grid, block, 0, stream>>>(x, wgt, out);
}

// Round 12
// 76.786 us; speedup vs baseline: 1.3279x; 1.0531x over previous
//
#include <hip/hip_runtime.h>
#include <hip/hip_bf16.h>

// 3D conv K=2 VALID + (y+1)^2, mfma_f32_32x32x16_bf16, vectorized streams.
// x: (8,16,64,64,64) f32; w: (32,128) f32, k = c*8 + kd*4 + kh*2 + kw.
// out: (8,32,63,63,63) f32.
//
// R11 (80.9 us) + ONE change: hybrid store granularity in the drain.
// R11's WRITE_SIZE (~290 MB vs 257 logical) = 2 partial 128-B lines per
// 2016-B run; NT partial lines bypass L2 and hit DRAM unmerged, even though
// the adjacent h-tile blocks write the complementary halves. Now the img
// shift aligns runs to 128-B lines (sh = base&31 dwords), head/tail fringes
// (<=31 dw each) use CACHED stores (L2 merges them across blocks), interior
// stays NT dwordx4.
//   - tile [2kd][2kh8][9h][64w][8c] bf16 (w-stride 16 B, conflict-free)
//   - strip [2][16c][64w] per-h double buffer, wave-private transpose
//   - 18x dwordx4 fused load burst (T14), LDS 40960 B = 4 blocks/CU
//   - grid (8,63,8) linear: d-neighbors same-XCD L2 reuse

typedef __attribute__((ext_vector_type(8)))  short short8;
typedef __attribute__((ext_vector_type(4)))  float f32x4;
typedef __attribute__((ext_vector_type(16))) float f32x16;
typedef __attribute__((ext_vector_type(4)))  unsigned short u16x4;

#define XCS 262144        // 64^3 x channel stride (f32)
#define OS  250047        // 63^3 out channel stride (f32)
#define SLAB_E 9216       // u16 per kd slab: [2 kh8][9 h][64 w][8 c]
#define KH8_E  4608       // 9*64*8
#define IMG_DW 536        // dwords per epilogue run slot (504 + 32 line pad)

__device__ __forceinline__ unsigned short f2bf(float f) {
    unsigned int u = __builtin_bit_cast(unsigned int, f);
    return (unsigned short)((u + 0x7fffu + ((u >> 16) & 1u)) >> 16);
}

__global__ __launch_bounds__(256, 4) void conv3d_k2_line(
    const float* __restrict__ x,
    const float* __restrict__ wgt,
    float* __restrict__ out)
{
    __shared__ __align__(16) unsigned char lds_raw[40960];
    unsigned short* tile  = (unsigned short*)lds_raw;            // [2][2][9][64][8] u16
    unsigned short* strip = (unsigned short*)(lds_raw + 36864);  // [2][16c][64w] u16
    float* img = (float*)lds_raw;                                 // [16][536] f32

    const int t   = threadIdx.x;
    const int l   = t & 63;
    const int wv  = t >> 6;        // wave 0..3
    const int col = l & 31;        // MFMA col (w) / A row (o)
    const int kh8 = l >> 5;        // k-half -> c8 group

    const int h0 = blockIdx.x * 8; // 8 output h rows
    const int d  = blockIdx.y;     // 0..62
    const int b  = blockIdx.z;

    // ---- A fragments: 64 contiguous floats per lane, compile-time shuffle ----
    short8 aF[8];
    {
        f32x4 wreg[16];
        const float* wp = wgt + col * 128 + kh8 * 64;
#pragma unroll
        for (int q = 0; q < 16; ++q) wreg[q] = *(const f32x4*)(wp + q * 4);
#pragma unroll
        for (int tap = 0; tap < 8; ++tap) {
            short8 a;
#pragma unroll
            for (int j = 0; j < 8; ++j) {
                const int k = j * 8 + tap;
                a[j] = (short)f2bf(wreg[k >> 2][k & 3]);
            }
            aF[tap] = a;
        }
    }

    // ---- staging: ONE 18x dwordx4 burst (both slabs), then LDS transpose ----
    const int cA   = t >> 4;       // c plane 0..15
    const int wq   = t & 15;       // 16-B w quad
    const int wB   = l;            // stage-B w
    const int kh8s = wv >> 1;
    const int half = wv & 1;

    f32x4 v[2][9];
#pragma unroll
    for (int p = 0; p < 2; ++p) {
        const float* xs = x + (size_t)b * 16 * XCS + (size_t)(d + p) * 4096
                            + (size_t)cA * XCS + wq * 4;
#pragma unroll
        for (int h = 0; h < 9; ++h) {
            int hp = h0 + h; if (hp > 63) hp = 63;
            v[p][h] = *(const f32x4*)(xs + hp * 64);
        }
    }

#pragma unroll
    for (int p = 0; p < 2; ++p) {
#pragma unroll
        for (int h = 0; h < 9; ++h) {
            unsigned short* sb = strip + (h & 1) * 1024;
            u16x4 pk;
#pragma unroll
            for (int i = 0; i < 4; ++i) pk[i] = f2bf(v[p][h][i]);
            *(u16x4*)&sb[cA * 64 + wq * 4] = pk;
            u16x4 q;
#pragma unroll
            for (int i = 0; i < 4; ++i)
                q[i] = sb[(wv * 4 + i) * 64 + wB];
            *(u16x4*)&tile[p * SLAB_E + kh8s * KH8_E + h * 512 + wB * 8 + half * 4] = q;
        }
    }
    __syncthreads();

    // ---- compute: 4 acc tiles (2 h-rows x 2 w-halves) kept in regs ----
    f32x16 acc[2][2];
#pragma unroll
    for (int th = 0; th < 2; ++th) {
        const int hl = wv * 2 + th;
#pragma unroll
        for (int wh = 0; wh < 2; ++wh) {
            const int wb = wh * 32;
            f32x16 a = {};
#pragma unroll
            for (int kd = 0; kd < 2; ++kd)
#pragma unroll
            for (int kh = 0; kh < 2; ++kh)
#pragma unroll
            for (int kw = 0; kw < 2; ++kw) {
                const int tap = kd * 4 + kh * 2 + kw;
                short8 bfrag = *(const short8*)&tile[kd * SLAB_E + kh8 * KH8_E
                    + (hl + kh) * 512 + (wb + col + kw) * 8];
                a = __builtin_amdgcn_mfma_f32_32x32x16_bf16(aF[tap], bfrag, a, 0, 0, 0);
            }
            acc[th][wh] = a;
        }
    }
    __syncthreads();   // done reading tile; LDS becomes the store image

    // ---- epilogue: 2 passes x 16 o-runs, line-aligned hybrid drain ----
    const int hvalid = (h0 == 56) ? 7 : 8;
    const int runlen = hvalid * 63;
#pragma unroll
    for (int p = 0; p < 2; ++p) {
        // scatter (y+1)^2 into img, shifted by each run's base&31 (128-B line)
#pragma unroll
        for (int th = 0; th < 2; ++th) {
            const int hl = wv * 2 + th;
            if (hl < hvalid) {
#pragma unroll
                for (int wh = 0; wh < 2; ++wh) {
                    const int wc = wh * 32 + col;
                    if (wc < 63) {
#pragma unroll
                        for (int r = 0; r < 8; ++r) {
                            const int rr = p * 8 + r;
                            const int og = (rr & 3) + 8 * (rr >> 2) + 4 * kh8;
                            const int ol = og - p * 16;
                            // base_dw mod 32: OS=-1, 3969=+1, 63=-1 (mod 32)
                            const int sh = (int)(((unsigned)(d - og - h0 + 1024)) & 31u);
                            float y = acc[th][wh][rr] + 1.0f;
                            img[ol * IMG_DW + sh + hl * 63 + wc] = y * y;
                        }
                    }
                }
            }
        }
        __syncthreads();
        // drain: wave wv owns 4 runs; cached fringes + NT line-aligned interior
#pragma unroll
        for (int orun = 0; orun < 4; ++orun) {
            const int ol = wv * 4 + orun;
            const int og = p * 16 + ol;
            const size_t base_dw = ((size_t)b * 32 + og) * (size_t)OS
                                 + (size_t)d * 3969 + (size_t)h0 * 63;
            float* gp = out + base_dw;
            const int sh = (int)(base_dw & 31);
            const float* ip = img + ol * IMG_DW + sh;
            int hc = (32 - sh) & 31;                 // head dwords (cached)
            if (hc > runlen) hc = runlen;
            if (l < hc) gp[l] = ip[l];
            const int ni = ((runlen - hc) >> 5) << 5; // interior (full 128-B lines)
            const int nv = ni >> 2;                   // x4 NT stores
#pragma unroll
            for (int rnd = 0; rnd < 2; ++rnd) {
                const int k = rnd * 64 + l;
                if (k < nv) {
                    f32x4 qv = *(const f32x4*)(ip + hc + 4 * k);
                    __builtin_nontemporal_store(qv, (f32x4*)(gp + hc + 4 * k));
                }
            }
            const int ts = hc + ni;                   // tail fringe (cached)
            if (ts + l < runlen) gp[ts + l] = ip[ts + l];
        }
        if (p == 0) __syncthreads();   // img reused by pass-1 scatter
    }
}

extern "C" void kernel_launch(void* const* d_in, const int* in_sizes, int n_in,
                              void* d_out, int out_size, void* d_ws, size_t ws_size,
                              hipStream_t stream) {
    const float* x   = (const float*)d_in[0];
    const float* wgt = (const float*)d_in[1];
    float* out = (float*)d_out;

    dim3 grid(8, 63, 8);    // h-tiles, d, b (linear = L2-friendly map)
    dim3 block(256);
    conv3d_k2_line<<<grid, block, 0, stream>>>(x, wgt, out);
}